// Round 3
// baseline (479.428 us; speedup 1.0000x reference)
//
#include <hip/hip_runtime.h>

#define NWIN 4096
#define EPSF 1e-6f
#define GRID_MAIN 512
#define BLOCK_MAIN 1024

// ---------------- workspace layout (bytes) ----------------
// header:
//  byte 0:  double sum_num      byte 8:  double sum_den
//  byte 16: u32 n_valid (u[4])  byte 20: u32 n_mask (u[5])
//  byte 24: f32 ref_dobs (f[6]) byte 28: f32 frac (f[7])
//  byte 32,36: u32 prefixes (u[8],u[9])   byte 40,44: u32 ranks (u[10],u[11])
#define OFF_SEG   256
#define OFF_H1    (OFF_SEG + 4 * NWIN * 4)      // 65792  (2048 u32)
#define OFF_H2    (OFF_H1 + 2048 * 4)           // 73984  (2 x 2048 u32)
#define OFF_H3    (OFF_H2 + 2 * 2048 * 4)       // 90368  (2 x 1024 u32)
#define OFF_PART  131072                        // GRID_MAIN x 64 KB partials
// keys (n x u32) follow the partials (or sit at OFF_PART if no partials)

__device__ __forceinline__ unsigned make_key_raw(const float4* __restrict__ xraw,
                                                 const int* __restrict__ mask,
                                                 const int* __restrict__ widx, int i)
{
    int wi = widx[i];
    int m = mask[i];
    if (wi < 0 || !m) return 0x7F800000u;   // +inf: sorts after all finite values
    float d = fmaxf(xraw[i].z, 0.0f);
    unsigned k = __float_as_uint(d);
    return (k == 0x80000000u) ? 0u : k;     // normalize -0.0
}

__device__ __forceinline__ unsigned get_key(const unsigned* __restrict__ keys,
                                            const float4* __restrict__ xraw,
                                            const int* __restrict__ mask,
                                            const int* __restrict__ widx,
                                            int use_keys, int i)
{
    if (use_keys) return keys[i];
    return make_key_raw(xraw, mask, widx, i);
}

// ---------------- main fused pass (CE + segsums + keys + hist1) ----------------
extern "C" __global__ __launch_bounds__(BLOCK_MAIN)
void k_main(const float2* __restrict__ logits, const int* __restrict__ y,
            const int* __restrict__ mask, const float4* __restrict__ xraw,
            const int* __restrict__ widx, const float* __restrict__ cw,
            double* __restrict__ ws_d, unsigned* __restrict__ ws_u,
            float* __restrict__ g_seg, float* __restrict__ part,
            unsigned* __restrict__ keys, unsigned* __restrict__ gh1,
            int use_part, int use_keys, int n)
{
    __shared__ float s_seg[4 * NWIN];    // 64 KB: cnt | sum_p | agg_rate | sum_pd
    __shared__ unsigned s_h1[2048];      // 8 KB: level-1 histogram (top 11 bits)
    for (int j = threadIdx.x; j < 4 * NWIN; j += BLOCK_MAIN) s_seg[j] = 0.0f;
    for (int j = threadIdx.x; j < 2048; j += BLOCK_MAIN) s_h1[j] = 0u;
    __syncthreads();

    const float cw0 = cw[0], cw1 = cw[1];
    float num = 0.0f, den = 0.0f;        // f32 in-thread; f64 only at global merge
    unsigned nv = 0u, nm = 0u, zc = 0u;

    for (int i = blockIdx.x * BLOCK_MAIN + threadIdx.x; i < n;
         i += GRID_MAIN * BLOCK_MAIN) {
        float2 lg = logits[i];
        int yi = y[i];
        int mi = mask[i];
        float4 xr = xraw[i];
        int wi = widx[i];

        float wy = yi ? cw1 : cw0;
        float mx = fmaxf(lg.x, lg.y);
        float lse = mx + __logf(__expf(lg.x - mx) + __expf(lg.y - mx));
        float nll = lse - (yi ? lg.y : lg.x);
        if (mi) {
            nm++;
            num += wy * nll;
            den += wy;
        }

        bool vq = (wi >= 0) && mi;
        unsigned key = 0x7F800000u;
        if (vq) {
            nv++;
            float d = fmaxf(xr.z, 0.0f);
            key = __float_as_uint(d);
            if (key == 0x80000000u) key = 0u;
        }
        if (use_keys) keys[i] = key;

        // fused level-1 histogram (zeros tallied in registers: huge tie at 0.0)
        if (key == 0u) zc++;
        else atomicAdd(&s_h1[key >> 21], 1u);

        if (vq && wi < NWIN) {           // segment_sum drops OOB indices
            float p = 1.0f / (1.0f + __expf(lg.x - lg.y));
            float rate = fmaxf(xr.w, 0.0f);
            float dob  = fmaxf(xr.z, 0.0f);
            atomicAdd(&s_seg[wi], 1.0f);
            atomicAdd(&s_seg[NWIN + wi], p);
            atomicAdd(&s_seg[2 * NWIN + wi], p * rate);
            atomicAdd(&s_seg[3 * NWIN + wi], p * dob);
        }
    }

    // wave(64) reduce, one global atomic per wave
    for (int off = 32; off > 0; off >>= 1) {
        num += __shfl_down(num, off);
        den += __shfl_down(den, off);
        nv  += __shfl_down(nv, off);
        nm  += __shfl_down(nm, off);
        zc  += __shfl_down(zc, off);
    }
    if ((threadIdx.x & 63) == 0) {
        atomicAdd(&ws_d[0], (double)num);
        atomicAdd(&ws_d[1], (double)den);
        atomicAdd(&ws_u[4], nv);
        atomicAdd(&ws_u[5], nm);
        if (zc) atomicAdd(&s_h1[0], zc);
    }
    __syncthreads();

    if (use_part) {
        // streaming flush: private 64 KB slice, coalesced float4, no atomics
        float4* dst = (float4*)(part + (size_t)blockIdx.x * (4 * NWIN));
        const float4* src = (const float4*)s_seg;
        for (int j = threadIdx.x; j < NWIN; j += BLOCK_MAIN) dst[j] = src[j];
    } else {
        for (int j = threadIdx.x; j < 4 * NWIN; j += BLOCK_MAIN) {
            float v = s_seg[j];
            if (v != 0.0f) atomicAdd(&g_seg[j], v);
        }
    }
    for (int j = threadIdx.x; j < 2048; j += BLOCK_MAIN) {
        unsigned v = s_h1[j];
        if (v) atomicAdd(&gh1[j], v);    // ~60 nonzero exponent bins/block only
    }
}

// ---------------- partial reduction: 512 partials -> g_seg ----------------
extern "C" __global__ __launch_bounds__(256)
void k_reduce(const float* __restrict__ part, float* __restrict__ g_seg)
{
    const int j = (blockIdx.x & 63) * 256 + threadIdx.x;   // bin 0..16383
    const int c = blockIdx.x >> 6;                         // chunk 0..7
    const float* p = part + (size_t)(c * (GRID_MAIN / 8)) * (4 * NWIN) + j;
    float s = 0.0f;
#pragma unroll 8
    for (int b = 0; b < GRID_MAIN / 8; ++b) s += p[(size_t)b * (4 * NWIN)];
    if (s != 0.0f) atomicAdd(&g_seg[j], s);                // <=131K atomics total
}

// ---------------- histogram passes 2 and 3 ----------------
extern "C" __global__ __launch_bounds__(256)
void k_hist2(const unsigned* __restrict__ keys, const float4* __restrict__ xraw,
             const int* __restrict__ mask, const int* __restrict__ widx,
             int use_keys, int n, const unsigned* __restrict__ ws_u,
             unsigned* __restrict__ gh)
{
    __shared__ unsigned h[2 * 2048];
    for (int j = threadIdx.x; j < 2 * 2048; j += 256) h[j] = 0u;
    __syncthreads();
    const unsigned p0 = ws_u[8], p1 = ws_u[9];   // 11-bit prefixes
    for (int i = blockIdx.x * blockDim.x + threadIdx.x; i < n;
         i += gridDim.x * blockDim.x) {
        unsigned key = get_key(keys, xraw, mask, widx, use_keys, i);
        unsigned top = key >> 21;
        unsigned sub = (key >> 10) & 2047u;
        if (top == p0) atomicAdd(&h[sub], 1u);
        if (top == p1) atomicAdd(&h[2048 + sub], 1u);
    }
    __syncthreads();
    for (int j = threadIdx.x; j < 2 * 2048; j += 256)
        if (h[j]) atomicAdd(&gh[j], h[j]);
}

extern "C" __global__ __launch_bounds__(256)
void k_hist3(const unsigned* __restrict__ keys, const float4* __restrict__ xraw,
             const int* __restrict__ mask, const int* __restrict__ widx,
             int use_keys, int n, const unsigned* __restrict__ ws_u,
             unsigned* __restrict__ gh)
{
    __shared__ unsigned h[2 * 1024];
    for (int j = threadIdx.x; j < 2 * 1024; j += 256) h[j] = 0u;
    __syncthreads();
    const unsigned p0 = ws_u[8], p1 = ws_u[9];   // 22-bit prefixes
    for (int i = blockIdx.x * blockDim.x + threadIdx.x; i < n;
         i += gridDim.x * blockDim.x) {
        unsigned key = get_key(keys, xraw, mask, widx, use_keys, i);
        unsigned top = key >> 10;
        unsigned sub = key & 1023u;
        if (top == p0) atomicAdd(&h[sub], 1u);
        if (top == p1) atomicAdd(&h[1024 + sub], 1u);
    }
    __syncthreads();
    for (int j = threadIdx.x; j < 2 * 1024; j += 256)
        if (h[j]) atomicAdd(&gh[j], h[j]);
}

// ---------------- single-block scan + rank search ----------------
__device__ void scan_search(const unsigned* __restrict__ gh, int NB, unsigned rank,
                            unsigned* sv, unsigned* wsb, unsigned* ret)
{
    const int tid = threadIdx.x;
    for (int j = tid; j < NB; j += 256) sv[j] = gh[j];
    __syncthreads();
    const int E = NB >> 8;
    const int base = tid * E;
    unsigned loc = 0u;
    for (int e = 0; e < E; ++e) loc += sv[base + e];
    unsigned inc = loc;
    const int lane = tid & 63;
    for (int off = 1; off < 64; off <<= 1) {
        unsigned u = __shfl_up(inc, off);
        if (lane >= off) inc += u;
    }
    const int wid = tid >> 6;
    if (lane == 63) wsb[wid] = inc;
    __syncthreads();
    if (tid == 0) {
        unsigned run = 0u;
        for (int w = 0; w < 4; ++w) { unsigned t = wsb[w]; wsb[w] = run; run += t; }
    }
    __syncthreads();
    unsigned c = wsb[wid] + (inc - loc);
    for (int e = 0; e < E; ++e) {
        unsigned hv = sv[base + e];
        if (rank >= c && rank < c + hv) { ret[0] = (unsigned)(base + e); ret[1] = rank - c; }
        c += hv;
    }
    __syncthreads();
}

extern "C" __global__ __launch_bounds__(256)
void k_scan1(unsigned* __restrict__ ws_u, float* __restrict__ ws_f,
             const unsigned* __restrict__ gh)
{
    __shared__ unsigned sv[2048];
    __shared__ unsigned wsb[4];
    __shared__ unsigned ret[2];
    __shared__ unsigned rk[2];
    if (threadIdx.x == 0) {
        int n = (int)ws_u[4];
        float nf = (float)(n - 1);              // f32 exactly like reference
        float pos = fmaxf(0.75f * nf, 0.0f);
        float lo = floorf(pos);
        ws_f[7] = pos - lo;                     // frac
        rk[0] = (unsigned)lo;
        rk[1] = (unsigned)ceilf(pos);
    }
    __syncthreads();
    unsigned r0 = rk[0], r1 = rk[1];
    scan_search(gh, 2048, r0, sv, wsb, ret);
    if (threadIdx.x == 0) { ws_u[8] = ret[0]; ws_u[10] = ret[1]; }
    scan_search(gh, 2048, r1, sv, wsb, ret);
    if (threadIdx.x == 0) { ws_u[9] = ret[0]; ws_u[11] = ret[1]; }
}

extern "C" __global__ __launch_bounds__(256)
void k_scan2(unsigned* __restrict__ ws_u, const unsigned* __restrict__ gh)
{
    __shared__ unsigned sv[2048];
    __shared__ unsigned wsb[4];
    __shared__ unsigned ret[2];
    unsigned p0 = ws_u[8], p1 = ws_u[9];
    unsigned r0 = ws_u[10], r1 = ws_u[11];
    scan_search(gh, 2048, r0, sv, wsb, ret);
    if (threadIdx.x == 0) { ws_u[8] = (p0 << 11) | ret[0]; ws_u[10] = ret[1]; }
    scan_search(gh + 2048, 2048, r1, sv, wsb, ret);
    if (threadIdx.x == 0) { ws_u[9] = (p1 << 11) | ret[0]; ws_u[11] = ret[1]; }
}

extern "C" __global__ __launch_bounds__(256)
void k_scan3(unsigned* __restrict__ ws_u, float* __restrict__ ws_f,
             const unsigned* __restrict__ gh)
{
    __shared__ unsigned sv[2048];
    __shared__ unsigned wsb[4];
    __shared__ unsigned ret[2];
    unsigned p0 = ws_u[8], p1 = ws_u[9];
    unsigned r0 = ws_u[10], r1 = ws_u[11];
    scan_search(gh, 1024, r0, sv, wsb, ret);
    float v0 = __uint_as_float((p0 << 10) | ret[0]);
    scan_search(gh + 1024, 1024, r1, sv, wsb, ret);
    float v1 = __uint_as_float((p1 << 10) | ret[0]);
    if (threadIdx.x == 0) {
        int n = (int)ws_u[4];
        float frac = ws_f[7];
        float q = v0 * (1.0f - frac) + v1 * frac;
        ws_f[6] = (n > 0) ? fmaxf(q, EPSF) : 1.0f;
    }
}

// ---------------- finalize over 4096 windows (double precision) ----------------
extern "C" __global__ __launch_bounds__(1024)
void k_final(const float* __restrict__ g_seg, const double* __restrict__ ws_d,
             const float* __restrict__ ws_f, const unsigned* __restrict__ ws_u,
             float* __restrict__ out)
{
    __shared__ double red[48];
    const double ref = (double)ws_f[6];
    double ninc = 0.0, fsum = 0.0, lsum = 0.0;
    for (int w = threadIdx.x; w < NWIN; w += blockDim.x) {
        double c   = (double)g_seg[w];
        double sp  = (double)g_seg[NWIN + w];
        double ar  = (double)g_seg[2 * NWIN + w];
        double spd = (double)g_seg[3 * NWIN + w];
        double inc = (c >= 2.0 && sp >= 1e-6) ? 1.0 : 0.0;
        double dmean = spd / (sp + 1e-6);
        double rr = ar / (1000.0 + 1e-6);
        double bu = fmax(rr - 1.0, 0.0);
        double flow = bu * bu;
        double rho = fmin(fmax(rr, 0.0), 0.99);
        double dth = 1.0 / (1.0 - rho + 1e-6);
        double lat = fmax(dth - dmean / ref, 0.0);
        ninc += inc; fsum += flow * inc; lsum += lat * inc;
    }
    for (int off = 32; off > 0; off >>= 1) {
        ninc += __shfl_down(ninc, off);
        fsum += __shfl_down(fsum, off);
        lsum += __shfl_down(lsum, off);
    }
    int wid = threadIdx.x >> 6, lane = threadIdx.x & 63;
    if (lane == 0) { red[wid] = ninc; red[16 + wid] = fsum; red[32 + wid] = lsum; }
    __syncthreads();
    if (threadIdx.x == 0) {
        double n_i = 0.0, f_s = 0.0, l_s = 0.0;
        int nw = (int)blockDim.x >> 6;
        for (int w = 0; w < nw; ++w) { n_i += red[w]; f_s += red[16 + w]; l_s += red[32 + w]; }
        double safe = fmax(n_i, 1.0);
        double l_flow = (n_i > 0.0) ? f_s / safe : 0.0;
        double l_lat  = (n_i > 0.0) ? l_s / safe : 0.0;
        double l_data = ws_d[0] / fmax(ws_d[1], 1e-12);
        bool any = ws_u[5] > 0u;
        if (!any) { l_data = 0.0; l_flow = 0.0; l_lat = 0.0; }
        out[0] = (float)(l_data + 0.1 * l_flow + 0.1 * l_lat);
        out[1] = (float)l_data;
        out[2] = (float)l_flow;
        out[3] = (float)l_lat;
    }
}

extern "C" void kernel_launch(void* const* d_in, const int* in_sizes, int n_in,
                              void* d_out, int out_size, void* d_ws, size_t ws_size,
                              hipStream_t stream)
{
    const float2* logits = (const float2*)d_in[0];
    const int* y = (const int*)d_in[1];
    const int* mask = (const int*)d_in[2];       // bool delivered as int32
    const float4* xraw = (const float4*)d_in[3];
    const int* widx = (const int*)d_in[4];
    const float* cw = (const float*)d_in[5];
    float* out = (float*)d_out;
    const int n = in_sizes[1];   // N from y

    unsigned char* ws8 = (unsigned char*)d_ws;
    double* ws_d = (double*)ws8;
    float* ws_f = (float*)ws8;
    unsigned* ws_u = (unsigned*)ws8;
    float* g_seg = (float*)(ws8 + OFF_SEG);
    unsigned* g_h1 = (unsigned*)(ws8 + OFF_H1);
    unsigned* g_h2 = (unsigned*)(ws8 + OFF_H2);
    unsigned* g_h3 = (unsigned*)(ws8 + OFF_H3);

    const size_t part_bytes = (size_t)GRID_MAIN * 4 * NWIN * 4;  // 32 MB
    const size_t keys_bytes = (size_t)n * 4u;
    float* part = (float*)(ws8 + OFF_PART);
    unsigned* keys = (unsigned*)(ws8 + OFF_PART);
    int use_part = 0, use_keys = 0;
    if (ws_size >= OFF_PART + part_bytes + keys_bytes) {
        use_part = 1; use_keys = 1;
        keys = (unsigned*)(ws8 + OFF_PART + part_bytes);
    } else if (ws_size >= OFF_PART + part_bytes) {
        use_part = 1;
    } else if (ws_size >= OFF_PART + keys_bytes) {
        use_keys = 1;
    }

    hipMemsetAsync(d_ws, 0, OFF_PART, stream);   // header + g_seg + hists

    k_main<<<GRID_MAIN, BLOCK_MAIN, 0, stream>>>(logits, y, mask, xraw, widx, cw,
                                                 ws_d, ws_u, g_seg, part, keys,
                                                 g_h1, use_part, use_keys, n);
    if (use_part)
        k_reduce<<<512, 256, 0, stream>>>(part, g_seg);
    k_scan1<<<1, 256, 0, stream>>>(ws_u, ws_f, g_h1);
    k_hist2<<<512, 256, 0, stream>>>(keys, xraw, mask, widx, use_keys, n, ws_u, g_h2);
    k_scan2<<<1, 256, 0, stream>>>(ws_u, g_h2);
    k_hist3<<<512, 256, 0, stream>>>(keys, xraw, mask, widx, use_keys, n, ws_u, g_h3);
    k_scan3<<<1, 256, 0, stream>>>(ws_u, ws_f, g_h3);
    k_final<<<1, 1024, 0, stream>>>(g_seg, ws_d, ws_f, ws_u, out);
}

// Round 4
// 306.680 us; speedup vs baseline: 1.5633x; 1.5633x over previous
//
#include <hip/hip_runtime.h>

#define NWIN 4096
#define EPSF 1e-6f
#define GRID_MAIN 512
#define BLOCK_MAIN 512

// ---------------- workspace layout (bytes) ----------------
// header:
//  byte 0:  double sum_num      byte 8:  double sum_den
//  byte 16: u32 n_valid (u[4])  byte 20: u32 n_mask (u[5])
//  byte 24: f32 ref_dobs (f[6]) byte 28: f32 frac (f[7])
//  byte 32,36: u32 prefixes (u[8],u[9])   byte 40,44: u32 ranks (u[10],u[11])
#define OFF_SEG   256
#define OFF_H1    (OFF_SEG + 4 * NWIN * 4)      // 65792  (2048 u32)
#define OFF_H2    (OFF_H1 + 2048 * 4)           // 73984  (2 x 2048 u32)
#define OFF_H3    (OFF_H2 + 2 * 2048 * 4)       // 90368  (2 x 1024 u32)
#define OFF_PART  131072                        // GRID_MAIN x 64 KB partials
// keys (n x u32) follow the partials (or sit at OFF_PART if no partials)

__device__ __forceinline__ unsigned make_key_raw(const float4* __restrict__ xraw,
                                                 const int* __restrict__ mask,
                                                 const int* __restrict__ widx, int i)
{
    int wi = widx[i];
    int m = mask[i];
    if (wi < 0 || !m) return 0x7F800000u;   // +inf: sorts after all finite values
    float d = fmaxf(xraw[i].z, 0.0f);
    unsigned k = __float_as_uint(d);
    return (k == 0x80000000u) ? 0u : k;     // normalize -0.0
}

// ---------------- per-element fused work ----------------
__device__ __forceinline__ void process_elem(
    float lgx, float lgy, int yi, int mi, float xz, float xw, int wi,
    float cw0, float cw1, unsigned* keyOut,
    float& num, float& den, unsigned& nv, unsigned& nm, unsigned& zc,
    float* s_seg, unsigned* s_h1)
{
    float wy = yi ? cw1 : cw0;
    float mx = fmaxf(lgx, lgy);
    float lse = mx + __logf(__expf(lgx - mx) + __expf(lgy - mx));
    float nll = lse - (yi ? lgy : lgx);
    if (mi) { nm++; num += wy * nll; den += wy; }

    bool vq = (wi >= 0) && mi;
    unsigned key = 0x7F800000u;
    if (vq) {
        nv++;
        float d = fmaxf(xz, 0.0f);
        key = __float_as_uint(d);
        if (key == 0x80000000u) key = 0u;
    }
    *keyOut = key;

    if (key == 0u) zc++;                    // huge tie at 0.0 stays in registers
    else atomicAdd(&s_h1[key >> 21], 1u);

    if (vq && wi < NWIN) {                  // segment_sum drops OOB indices
        float p = 1.0f / (1.0f + __expf(lgx - lgy));
        float rate = fmaxf(xw, 0.0f);
        float dob  = fmaxf(xz, 0.0f);
        atomicAdd(&s_seg[wi], 1.0f);
        atomicAdd(&s_seg[NWIN + wi], p);
        atomicAdd(&s_seg[2 * NWIN + wi], p * rate);
        atomicAdd(&s_seg[3 * NWIN + wi], p * dob);
    }
}

// ---------------- main fused pass (CE + segsums + keys + hist1) ----------------
// 4 elements per thread per iteration: 9 wide loads issued before any use -> MLP.
extern "C" __global__ __launch_bounds__(BLOCK_MAIN, 4)
void k_main(const float2* __restrict__ logits, const int* __restrict__ y,
            const int* __restrict__ mask, const float4* __restrict__ xraw,
            const int* __restrict__ widx, const float* __restrict__ cw,
            double* __restrict__ ws_d, unsigned* __restrict__ ws_u,
            float* __restrict__ g_seg, float* __restrict__ part,
            unsigned* __restrict__ keys, unsigned* __restrict__ gh1,
            int use_part, int use_keys, int n)
{
    __shared__ float s_seg[4 * NWIN];    // 64 KB: cnt | sum_p | agg_rate | sum_pd
    __shared__ unsigned s_h1[2048];      // 8 KB: level-1 histogram (top 11 bits)
    for (int j = threadIdx.x; j < 4 * NWIN; j += BLOCK_MAIN) s_seg[j] = 0.0f;
    for (int j = threadIdx.x; j < 2048; j += BLOCK_MAIN) s_h1[j] = 0u;
    __syncthreads();

    const float cw0 = cw[0], cw1 = cw[1];
    float num = 0.0f, den = 0.0f;
    unsigned nv = 0u, nm = 0u, zc = 0u;

    const int nth = GRID_MAIN * BLOCK_MAIN;
    const int gtid = blockIdx.x * BLOCK_MAIN + threadIdx.x;
    const int nq = n >> 2;

    const float4* lg4 = (const float4*)logits;
    const int4* y4p = (const int4*)y;
    const int4* m4p = (const int4*)mask;
    const int4* w4p = (const int4*)widx;

    for (int q = gtid; q < nq; q += nth) {
        // issue all 9 wide loads up front
        float4 lgA = lg4[2 * q];
        float4 lgB = lg4[2 * q + 1];
        int4 y4 = y4p[q];
        int4 m4 = m4p[q];
        int4 w4 = w4p[q];
        float4 x0 = xraw[4 * q];
        float4 x1 = xraw[4 * q + 1];
        float4 x2 = xraw[4 * q + 2];
        float4 x3 = xraw[4 * q + 3];

        uint4 kq;
        process_elem(lgA.x, lgA.y, y4.x, m4.x, x0.z, x0.w, w4.x,
                     cw0, cw1, &kq.x, num, den, nv, nm, zc, s_seg, s_h1);
        process_elem(lgA.z, lgA.w, y4.y, m4.y, x1.z, x1.w, w4.y,
                     cw0, cw1, &kq.y, num, den, nv, nm, zc, s_seg, s_h1);
        process_elem(lgB.x, lgB.y, y4.z, m4.z, x2.z, x2.w, w4.z,
                     cw0, cw1, &kq.z, num, den, nv, nm, zc, s_seg, s_h1);
        process_elem(lgB.z, lgB.w, y4.w, m4.w, x3.z, x3.w, w4.w,
                     cw0, cw1, &kq.w, num, den, nv, nm, zc, s_seg, s_h1);
        if (use_keys) ((uint4*)keys)[q] = kq;
    }
    // scalar tail (n % 4 != 0)
    for (int i = (nq << 2) + gtid; i < n; i += nth) {
        float2 lg = logits[i];
        float4 xr = xraw[i];
        unsigned k;
        process_elem(lg.x, lg.y, y[i], mask[i], xr.z, xr.w, widx[i],
                     cw0, cw1, &k, num, den, nv, nm, zc, s_seg, s_h1);
        if (use_keys) keys[i] = k;
    }

    // wave(64) reduce, one global atomic per wave
    for (int off = 32; off > 0; off >>= 1) {
        num += __shfl_down(num, off);
        den += __shfl_down(den, off);
        nv  += __shfl_down(nv, off);
        nm  += __shfl_down(nm, off);
        zc  += __shfl_down(zc, off);
    }
    if ((threadIdx.x & 63) == 0) {
        atomicAdd(&ws_d[0], (double)num);
        atomicAdd(&ws_d[1], (double)den);
        atomicAdd(&ws_u[4], nv);
        atomicAdd(&ws_u[5], nm);
        if (zc) atomicAdd(&s_h1[0], zc);
    }
    __syncthreads();

    if (use_part) {
        // streaming flush: private 64 KB slice, coalesced float4, no atomics
        float4* dst = (float4*)(part + (size_t)blockIdx.x * (4 * NWIN));
        const float4* src = (const float4*)s_seg;
        for (int j = threadIdx.x; j < NWIN; j += BLOCK_MAIN) dst[j] = src[j];
    } else {
        for (int j = threadIdx.x; j < 4 * NWIN; j += BLOCK_MAIN) {
            float v = s_seg[j];
            if (v != 0.0f) atomicAdd(&g_seg[j], v);
        }
    }
    for (int j = threadIdx.x; j < 2048; j += BLOCK_MAIN) {
        unsigned v = s_h1[j];
        if (v) atomicAdd(&gh1[j], v);    // ~60 nonzero exponent bins/block only
    }
}

// ---------------- partial reduction: 512 partials -> g_seg ----------------
extern "C" __global__ __launch_bounds__(256)
void k_reduce(const float* __restrict__ part, float* __restrict__ g_seg)
{
    const int j = (blockIdx.x & 63) * 256 + threadIdx.x;   // bin 0..16383
    const int c = blockIdx.x >> 6;                         // chunk 0..7
    const float* p = part + (size_t)(c * (GRID_MAIN / 8)) * (4 * NWIN) + j;
    float s = 0.0f;
#pragma unroll 8
    for (int b = 0; b < GRID_MAIN / 8; ++b) s += p[(size_t)b * (4 * NWIN)];
    if (s != 0.0f) atomicAdd(&g_seg[j], s);                // <=131K atomics total
}

// ---------------- histogram passes 2 and 3 ----------------
extern "C" __global__ __launch_bounds__(256)
void k_hist2(const unsigned* __restrict__ keys, const float4* __restrict__ xraw,
             const int* __restrict__ mask, const int* __restrict__ widx,
             int use_keys, int n, const unsigned* __restrict__ ws_u,
             unsigned* __restrict__ gh)
{
    __shared__ unsigned h[2 * 2048];
    for (int j = threadIdx.x; j < 2 * 2048; j += 256) h[j] = 0u;
    __syncthreads();
    const unsigned p0 = ws_u[8], p1 = ws_u[9];   // 11-bit prefixes
    const int nth = gridDim.x * blockDim.x;
    const int gtid = blockIdx.x * blockDim.x + threadIdx.x;
    if (use_keys) {
        const uint4* k4 = (const uint4*)keys;
        const int nq = n >> 2;
        for (int q = gtid; q < nq; q += nth) {
            uint4 kk = k4[q];
#pragma unroll
            for (int e = 0; e < 4; ++e) {
                unsigned key = (e == 0) ? kk.x : (e == 1) ? kk.y : (e == 2) ? kk.z : kk.w;
                unsigned top = key >> 21;
                unsigned sub = (key >> 10) & 2047u;
                if (top == p0) atomicAdd(&h[sub], 1u);
                if (top == p1) atomicAdd(&h[2048 + sub], 1u);
            }
        }
        for (int i = (nq << 2) + gtid; i < n; i += nth) {
            unsigned key = keys[i];
            unsigned top = key >> 21;
            unsigned sub = (key >> 10) & 2047u;
            if (top == p0) atomicAdd(&h[sub], 1u);
            if (top == p1) atomicAdd(&h[2048 + sub], 1u);
        }
    } else {
        for (int i = gtid; i < n; i += nth) {
            unsigned key = make_key_raw(xraw, mask, widx, i);
            unsigned top = key >> 21;
            unsigned sub = (key >> 10) & 2047u;
            if (top == p0) atomicAdd(&h[sub], 1u);
            if (top == p1) atomicAdd(&h[2048 + sub], 1u);
        }
    }
    __syncthreads();
    for (int j = threadIdx.x; j < 2 * 2048; j += 256)
        if (h[j]) atomicAdd(&gh[j], h[j]);
}

extern "C" __global__ __launch_bounds__(256)
void k_hist3(const unsigned* __restrict__ keys, const float4* __restrict__ xraw,
             const int* __restrict__ mask, const int* __restrict__ widx,
             int use_keys, int n, const unsigned* __restrict__ ws_u,
             unsigned* __restrict__ gh)
{
    __shared__ unsigned h[2 * 1024];
    for (int j = threadIdx.x; j < 2 * 1024; j += 256) h[j] = 0u;
    __syncthreads();
    const unsigned p0 = ws_u[8], p1 = ws_u[9];   // 22-bit prefixes
    const int nth = gridDim.x * blockDim.x;
    const int gtid = blockIdx.x * blockDim.x + threadIdx.x;
    if (use_keys) {
        const uint4* k4 = (const uint4*)keys;
        const int nq = n >> 2;
        for (int q = gtid; q < nq; q += nth) {
            uint4 kk = k4[q];
#pragma unroll
            for (int e = 0; e < 4; ++e) {
                unsigned key = (e == 0) ? kk.x : (e == 1) ? kk.y : (e == 2) ? kk.z : kk.w;
                unsigned top = key >> 10;
                unsigned sub = key & 1023u;
                if (top == p0) atomicAdd(&h[sub], 1u);
                if (top == p1) atomicAdd(&h[1024 + sub], 1u);
            }
        }
        for (int i = (nq << 2) + gtid; i < n; i += nth) {
            unsigned key = keys[i];
            unsigned top = key >> 10;
            unsigned sub = key & 1023u;
            if (top == p0) atomicAdd(&h[sub], 1u);
            if (top == p1) atomicAdd(&h[1024 + sub], 1u);
        }
    } else {
        for (int i = gtid; i < n; i += nth) {
            unsigned key = make_key_raw(xraw, mask, widx, i);
            unsigned top = key >> 10;
            unsigned sub = key & 1023u;
            if (top == p0) atomicAdd(&h[sub], 1u);
            if (top == p1) atomicAdd(&h[1024 + sub], 1u);
        }
    }
    __syncthreads();
    for (int j = threadIdx.x; j < 2 * 1024; j += 256)
        if (h[j]) atomicAdd(&gh[j], h[j]);
}

// ---------------- single-block scan + rank search ----------------
__device__ void scan_search(const unsigned* __restrict__ gh, int NB, unsigned rank,
                            unsigned* sv, unsigned* wsb, unsigned* ret)
{
    const int tid = threadIdx.x;
    for (int j = tid; j < NB; j += 256) sv[j] = gh[j];
    __syncthreads();
    const int E = NB >> 8;
    const int base = tid * E;
    unsigned loc = 0u;
    for (int e = 0; e < E; ++e) loc += sv[base + e];
    unsigned inc = loc;
    const int lane = tid & 63;
    for (int off = 1; off < 64; off <<= 1) {
        unsigned u = __shfl_up(inc, off);
        if (lane >= off) inc += u;
    }
    const int wid = tid >> 6;
    if (lane == 63) wsb[wid] = inc;
    __syncthreads();
    if (tid == 0) {
        unsigned run = 0u;
        for (int w = 0; w < 4; ++w) { unsigned t = wsb[w]; wsb[w] = run; run += t; }
    }
    __syncthreads();
    unsigned c = wsb[wid] + (inc - loc);
    for (int e = 0; e < E; ++e) {
        unsigned hv = sv[base + e];
        if (rank >= c && rank < c + hv) { ret[0] = (unsigned)(base + e); ret[1] = rank - c; }
        c += hv;
    }
    __syncthreads();
}

extern "C" __global__ __launch_bounds__(256)
void k_scan1(unsigned* __restrict__ ws_u, float* __restrict__ ws_f,
             const unsigned* __restrict__ gh)
{
    __shared__ unsigned sv[2048];
    __shared__ unsigned wsb[4];
    __shared__ unsigned ret[2];
    __shared__ unsigned rk[2];
    if (threadIdx.x == 0) {
        int n = (int)ws_u[4];
        float nf = (float)(n - 1);              // f32 exactly like reference
        float pos = fmaxf(0.75f * nf, 0.0f);
        float lo = floorf(pos);
        ws_f[7] = pos - lo;                     // frac
        rk[0] = (unsigned)lo;
        rk[1] = (unsigned)ceilf(pos);
    }
    __syncthreads();
    unsigned r0 = rk[0], r1 = rk[1];
    scan_search(gh, 2048, r0, sv, wsb, ret);
    if (threadIdx.x == 0) { ws_u[8] = ret[0]; ws_u[10] = ret[1]; }
    scan_search(gh, 2048, r1, sv, wsb, ret);
    if (threadIdx.x == 0) { ws_u[9] = ret[0]; ws_u[11] = ret[1]; }
}

extern "C" __global__ __launch_bounds__(256)
void k_scan2(unsigned* __restrict__ ws_u, const unsigned* __restrict__ gh)
{
    __shared__ unsigned sv[2048];
    __shared__ unsigned wsb[4];
    __shared__ unsigned ret[2];
    unsigned p0 = ws_u[8], p1 = ws_u[9];
    unsigned r0 = ws_u[10], r1 = ws_u[11];
    scan_search(gh, 2048, r0, sv, wsb, ret);
    if (threadIdx.x == 0) { ws_u[8] = (p0 << 11) | ret[0]; ws_u[10] = ret[1]; }
    scan_search(gh + 2048, 2048, r1, sv, wsb, ret);
    if (threadIdx.x == 0) { ws_u[9] = (p1 << 11) | ret[0]; ws_u[11] = ret[1]; }
}

extern "C" __global__ __launch_bounds__(256)
void k_scan3(unsigned* __restrict__ ws_u, float* __restrict__ ws_f,
             const unsigned* __restrict__ gh)
{
    __shared__ unsigned sv[2048];
    __shared__ unsigned wsb[4];
    __shared__ unsigned ret[2];
    unsigned p0 = ws_u[8], p1 = ws_u[9];
    unsigned r0 = ws_u[10], r1 = ws_u[11];
    scan_search(gh, 1024, r0, sv, wsb, ret);
    float v0 = __uint_as_float((p0 << 10) | ret[0]);
    scan_search(gh + 1024, 1024, r1, sv, wsb, ret);
    float v1 = __uint_as_float((p1 << 10) | ret[0]);
    if (threadIdx.x == 0) {
        int n = (int)ws_u[4];
        float frac = ws_f[7];
        float q = v0 * (1.0f - frac) + v1 * frac;
        ws_f[6] = (n > 0) ? fmaxf(q, EPSF) : 1.0f;
    }
}

// ---------------- finalize over 4096 windows (double precision) ----------------
extern "C" __global__ __launch_bounds__(1024)
void k_final(const float* __restrict__ g_seg, const double* __restrict__ ws_d,
             const float* __restrict__ ws_f, const unsigned* __restrict__ ws_u,
             float* __restrict__ out)
{
    __shared__ double red[48];
    const double ref = (double)ws_f[6];
    double ninc = 0.0, fsum = 0.0, lsum = 0.0;
    for (int w = threadIdx.x; w < NWIN; w += blockDim.x) {
        double c   = (double)g_seg[w];
        double sp  = (double)g_seg[NWIN + w];
        double ar  = (double)g_seg[2 * NWIN + w];
        double spd = (double)g_seg[3 * NWIN + w];
        double inc = (c >= 2.0 && sp >= 1e-6) ? 1.0 : 0.0;
        double dmean = spd / (sp + 1e-6);
        double rr = ar / (1000.0 + 1e-6);
        double bu = fmax(rr - 1.0, 0.0);
        double flow = bu * bu;
        double rho = fmin(fmax(rr, 0.0), 0.99);
        double dth = 1.0 / (1.0 - rho + 1e-6);
        double lat = fmax(dth - dmean / ref, 0.0);
        ninc += inc; fsum += flow * inc; lsum += lat * inc;
    }
    for (int off = 32; off > 0; off >>= 1) {
        ninc += __shfl_down(ninc, off);
        fsum += __shfl_down(fsum, off);
        lsum += __shfl_down(lsum, off);
    }
    int wid = threadIdx.x >> 6, lane = threadIdx.x & 63;
    if (lane == 0) { red[wid] = ninc; red[16 + wid] = fsum; red[32 + wid] = lsum; }
    __syncthreads();
    if (threadIdx.x == 0) {
        double n_i = 0.0, f_s = 0.0, l_s = 0.0;
        int nw = (int)blockDim.x >> 6;
        for (int w = 0; w < nw; ++w) { n_i += red[w]; f_s += red[16 + w]; l_s += red[32 + w]; }
        double safe = fmax(n_i, 1.0);
        double l_flow = (n_i > 0.0) ? f_s / safe : 0.0;
        double l_lat  = (n_i > 0.0) ? l_s / safe : 0.0;
        double l_data = ws_d[0] / fmax(ws_d[1], 1e-12);
        bool any = ws_u[5] > 0u;
        if (!any) { l_data = 0.0; l_flow = 0.0; l_lat = 0.0; }
        out[0] = (float)(l_data + 0.1 * l_flow + 0.1 * l_lat);
        out[1] = (float)l_data;
        out[2] = (float)l_flow;
        out[3] = (float)l_lat;
    }
}

extern "C" void kernel_launch(void* const* d_in, const int* in_sizes, int n_in,
                              void* d_out, int out_size, void* d_ws, size_t ws_size,
                              hipStream_t stream)
{
    const float2* logits = (const float2*)d_in[0];
    const int* y = (const int*)d_in[1];
    const int* mask = (const int*)d_in[2];       // bool delivered as int32
    const float4* xraw = (const float4*)d_in[3];
    const int* widx = (const int*)d_in[4];
    const float* cw = (const float*)d_in[5];
    float* out = (float*)d_out;
    const int n = in_sizes[1];   // N from y

    unsigned char* ws8 = (unsigned char*)d_ws;
    double* ws_d = (double*)ws8;
    float* ws_f = (float*)ws8;
    unsigned* ws_u = (unsigned*)ws8;
    float* g_seg = (float*)(ws8 + OFF_SEG);
    unsigned* g_h1 = (unsigned*)(ws8 + OFF_H1);
    unsigned* g_h2 = (unsigned*)(ws8 + OFF_H2);
    unsigned* g_h3 = (unsigned*)(ws8 + OFF_H3);

    const size_t part_bytes = (size_t)GRID_MAIN * 4 * NWIN * 4;  // 32 MB
    const size_t keys_bytes = (size_t)n * 4u;
    float* part = (float*)(ws8 + OFF_PART);
    unsigned* keys = (unsigned*)(ws8 + OFF_PART);
    int use_part = 0, use_keys = 0;
    if (ws_size >= OFF_PART + part_bytes + keys_bytes) {
        use_part = 1; use_keys = 1;
        keys = (unsigned*)(ws8 + OFF_PART + part_bytes);
    } else if (ws_size >= OFF_PART + part_bytes) {
        use_part = 1;
    } else if (ws_size >= OFF_PART + keys_bytes) {
        use_keys = 1;
    }

    hipMemsetAsync(d_ws, 0, OFF_PART, stream);   // header + g_seg + hists

    k_main<<<GRID_MAIN, BLOCK_MAIN, 0, stream>>>(logits, y, mask, xraw, widx, cw,
                                                 ws_d, ws_u, g_seg, part, keys,
                                                 g_h1, use_part, use_keys, n);
    if (use_part)
        k_reduce<<<512, 256, 0, stream>>>(part, g_seg);
    k_scan1<<<1, 256, 0, stream>>>(ws_u, ws_f, g_h1);
    k_hist2<<<512, 256, 0, stream>>>(keys, xraw, mask, widx, use_keys, n, ws_u, g_h2);
    k_scan2<<<1, 256, 0, stream>>>(ws_u, g_h2);
    k_hist3<<<512, 256, 0, stream>>>(keys, xraw, mask, widx, use_keys, n, ws_u, g_h3);
    k_scan3<<<1, 256, 0, stream>>>(ws_u, ws_f, g_h3);
    k_final<<<1, 1024, 0, stream>>>(g_seg, ws_d, ws_f, ws_u, out);
}